// Round 1
// baseline (87.496 us; speedup 1.0000x reference)
//
#include <hip/hip_runtime.h>

// L1 attention: attn[b,s,t,h] = -sum_w |q[b,s,h,w] - k[b,t,h,w]| / sqrt(W)
// B=1, S=T=1024, H=8, W=32, fp32 in / fp32 out.
//
// Block: 256 threads (4 waves). Tile: 16 s x 64 t x 8 h.
// - k tile (64 KB) staged in LDS, float4-chunk XOR swizzle (j ^ (row&7))
//   so per-phase b128 reads are bank-conflict-free.
// - lane -> (t_local = lane>>3, h = lane&7): wave stores 64 contiguous dwords.
// - each thread keeps 4 q rows (128 VGPR) -> 4 outputs per k-row LDS read.

constexpr int S_DIM = 1024;
constexpr int T_DIM = 1024;
constexpr int H_DIM = 8;
constexpr int W_DIM = 32;
constexpr int TT = 64;   // t per block
constexpr int SB = 16;   // s per block
constexpr int MS = 4;    // s per thread (per wave)

__global__ __launch_bounds__(256, 2)
void l1attn_kernel(const float* __restrict__ q,
                   const float* __restrict__ k,
                   float* __restrict__ out) {
    const int tid  = threadIdx.x;
    const int lane = tid & 63;
    const int wv   = tid >> 6;
    const int t0   = blockIdx.x * TT;
    const int s0   = blockIdx.y * SB + wv * MS;
    const int h    = lane & 7;
    const int tl   = lane >> 3;

    __shared__ float4 klds[TT * H_DIM * (W_DIM / 4)];  // 4096 float4 = 64 KB

    // ---- q rows into registers: 4 s values, this lane's h (128B each) ----
    float qreg[MS][W_DIM];
    #pragma unroll
    for (int si = 0; si < MS; ++si) {
        const float4* qrow =
            (const float4*)(q + ((size_t)(s0 + si) * H_DIM + h) * W_DIM);
        #pragma unroll
        for (int j = 0; j < 8; ++j) {
            float4 v = qrow[j];
            qreg[si][4 * j + 0] = v.x;
            qreg[si][4 * j + 1] = v.y;
            qreg[si][4 * j + 2] = v.z;
            qreg[si][4 * j + 3] = v.w;
        }
    }

    // ---- stage k tile (contiguous 64 KB in global) into swizzled LDS ----
    const float4* k4 = (const float4*)(k + (size_t)t0 * H_DIM * W_DIM);
    #pragma unroll
    for (int p = 0; p < 16; ++p) {
        int f = p * 256 + tid;   // float4 index within tile, 0..4095
        int r = f >> 3;          // row = t_local*8 + h, 0..511
        int j = f & 7;           // 16B chunk within the 128B row
        klds[r * 8 + (j ^ (r & 7))] = k4[f];
    }
    __syncthreads();

    const float nscale = -0.17677669529663688f;  // -1/sqrt(32)

    for (int tg = 0; tg < 8; ++tg) {
        const int r = tg * 64 + lane;            // LDS row; r&7 == h
        const float4* krow = klds + r * 8;
        float kreg[W_DIM];
        #pragma unroll
        for (int j = 0; j < 8; ++j) {
            float4 v = krow[j ^ h];
            kreg[4 * j + 0] = v.x;
            kreg[4 * j + 1] = v.y;
            kreg[4 * j + 2] = v.z;
            kreg[4 * j + 3] = v.w;
        }
        const int t = t0 + tg * 8 + tl;
        #pragma unroll
        for (int si = 0; si < MS; ++si) {
            float a = 0.0f;
            #pragma unroll
            for (int w = 0; w < W_DIM; ++w)
                a += fabsf(qreg[si][w] - kreg[w]);  // v_sub + v_add(abs) = 2 ops
            out[((size_t)(s0 + si) * T_DIM + t) * H_DIM + h] = a * nscale;
        }
    }
}

extern "C" void kernel_launch(void* const* d_in, const int* in_sizes, int n_in,
                              void* d_out, int out_size, void* d_ws, size_t ws_size,
                              hipStream_t stream) {
    const float* q = (const float*)d_in[0];
    const float* k = (const float*)d_in[1];
    float* out = (float*)d_out;
    dim3 grid(T_DIM / TT, S_DIM / SB);  // (16, 64)
    l1attn_kernel<<<grid, dim3(256, 1, 1), 0, stream>>>(q, k, out);
}